// Round 10
// baseline (415.695 us; speedup 1.0000x reference)
//
#include <hip/hip_runtime.h>
#include <hip/hip_bf16.h>

typedef __hip_bfloat16 bf16;
typedef unsigned int uint32;
typedef __attribute__((ext_vector_type(8))) short s8v;   // 8 bf16 (16B)
typedef __attribute__((ext_vector_type(4))) short s4v;   // 4 bf16 (8B)
typedef __attribute__((ext_vector_type(8))) short bf8v;  // MFMA A/B frag
typedef __attribute__((ext_vector_type(4))) float f4v;   // MFMA accumulator

#define CAP 64          // bucket capacity per destination row (deg ~ Poisson(16); P(>64) ~ 1e-20)
#define CAPSH 6

__device__ __forceinline__ float waveReduce(float v) {
#pragma unroll
    for (int o = 32; o > 0; o >>= 1) v += __shfl_xor(v, o, 64);
    return v;
}

__device__ __forceinline__ short f2bf(float x) {
    __hip_bfloat16 h = __float2bfloat16(x);
    return *reinterpret_cast<short*>(&h);
}
__device__ __forceinline__ float bf2f(short s) {
    return __uint_as_float(((uint32)(unsigned short)s) << 16);
}
__device__ __forceinline__ uint32 pack2(float x, float y) {
    return (uint32)(unsigned short)f2bf(x) | (((uint32)(unsigned short)f2bf(y)) << 16);
}
__device__ __forceinline__ float blo(uint32 d) { return __uint_as_float(d << 16); }
__device__ __forceinline__ float bhi(uint32 d) { return __uint_as_float(d & 0xffff0000u); }
// fast ELU: expm1f library call -> native v_exp_f32 path (error << bf16 rounding)
__device__ __forceinline__ float felu(float x) { return x > 0.f ? x : __expf(x) - 1.f; }

// ------- batched weight transpose + cursor init + attsum clear + vab + edge prepack -------
struct WJobs {
    const float* src[5];
    short* dst[5];
    int K[5], N[5], KP[5], total[5];
    int* cursor;
    float* attsum;
    float* vab;           // [256]: tw{src,dst} then tu{src,dst}, 64 floats each
    const float* W2tw; const float* a2tw;
    const float* W2tu; const float* a2tu;
    int N2;
    // edge prepack (rows/cols < 65536 -> one uint32 per edge)
    const int* rowA; const int* colA;
    const int* rowB; const int* colB;
    uint32* epkA; uint32* epkB;
    int E;
};
__global__ void wtrans_all(WJobs jb) {
    int j = blockIdx.y;
    int i = blockIdx.x * blockDim.x + threadIdx.x;
    if (j == 5) {   // aux: cursor init + attsum clear + vab = W2^T a2
        if (i < jb.N2) jb.cursor[i] = i << CAPSH;
        if (i < 2) jb.attsum[i] = 0.f;
        if (i < 256) {
            int br = i >> 7;          // 0=tw 1=tu
            int half = (i >> 6) & 1;  // 0=src 1=dst
            int k = i & 63;
            const float* W2 = br ? jb.W2tu : jb.W2tw;   // [64][128] row-major
            const float* a2 = br ? jb.a2tu : jb.a2tw;   // [256]
            float s = 0.f;
#pragma unroll 4
            for (int q = 0; q < 128; ++q) s += W2[k * 128 + q] * a2[half * 128 + q];
            jb.vab[i] = s;
        }
        return;
    }
    if (j == 6) {   // prepack tweet edges
        if (jb.epkA && i < jb.E)
            jb.epkA[i] = ((uint32)jb.rowA[i] << 16) | (uint32)jb.colA[i];
        return;
    }
    if (j == 7) {   // prepack user edges
        if (jb.epkB && i < jb.E)
            jb.epkB[i] = ((uint32)jb.rowB[i] << 16) | (uint32)jb.colB[i];
        return;
    }
    if (i >= jb.total[j]) return;
    int KP = jb.KP[j];
    int n = i / KP, k = i - n * KP;
    jb.dst[j][i] = f2bf(k < jb.K[j] ? jb.src[j][(size_t)k * jb.N[j] + n] : 0.f);
}

// ---------------- packed XCD-windowed bucket scatter ----------------
// 4 windows per graph (w<4: tweet via epkA, w>=4: user via epkB). Window slice = 3.2MB of
// buckets, L2-resident per XCD (w = blockIdx&7 matches round-robin blockIdx->XCD). Packed
// edges quarter the re-read volume vs raw row/col (25.6MB total vs 102MB).
__global__ void scatter8p_kernel(const uint32* __restrict__ epkA, const uint32* __restrict__ epkB,
                                 int* __restrict__ cursor, int* __restrict__ ecol,
                                 int E, int NTW, int UV, int Wt, int Wu) {
    int w = (int)blockIdx.x & 7;
    int i = ((int)blockIdx.x >> 3) * 256 + (int)threadIdx.x;
    if (i >= E) return;
    if (w < 4) {
        uint32 pk = __builtin_nontemporal_load(epkA + i);
        int r = (int)(pk >> 16);
        int lo = w * Wt;
        int hi = lo + Wt; if (hi > NTW) hi = NTW;
        if (r >= lo && r < hi) {
            int p0 = atomicAdd(&cursor[r], 1);
            if (p0 < (r << CAPSH) + CAP) ecol[p0] = (int)(pk & 0xffffu);
        }
    } else {
        uint32 pk = __builtin_nontemporal_load(epkB + i);
        int r = (int)(pk >> 16);
        int lo = (w - 4) * Wu;
        int hi = lo + Wu; if (hi > UV) hi = UV;
        if (r >= lo && r < hi) {
            int rg = NTW + r;
            int p0 = atomicAdd(&cursor[rg], 1);
            if (p0 < (rg << CAPSH) + CAP) ecol[p0] = (int)(pk & 0xffffu);
        }
    }
}

// fallback (raw row/col) for sizes >= 65536 — R9 behavior
__global__ void scatter8_kernel(const int* __restrict__ rowA, const int* __restrict__ colA,
                                const int* __restrict__ rowB, const int* __restrict__ colB,
                                int* __restrict__ cursor, int* __restrict__ ecol,
                                int E, int NTW, int Wsize) {
    int w = (int)blockIdx.x & 7;
    int i = ((int)blockIdx.x >> 3) * 256 + (int)threadIdx.x;
    int lo = w * Wsize, hi = lo + Wsize;
    int r = -1, c = 0;
    if (i < E) {
        r = __builtin_nontemporal_load(rowA + i);
        c = __builtin_nontemporal_load(colA + i);
    } else if (i < 2 * E) {
        r = NTW + __builtin_nontemporal_load(rowB + (i - E));
        c = __builtin_nontemporal_load(colB + (i - E));
    }
    if (r >= lo && r < hi) {
        int p0 = atomicAdd(&cursor[r], 1);
        if (p0 < (r << CAPSH) + CAP) ecol[p0] = c;
    }
}

// ---------------- universal MFMA GEMM (2-job block-range dispatch) ----------------
// CSTORE: 0=none, 1=f32, 2=bf16, 3=bf16 with fused ELU
// DO_ATT2: fused attention reduce — after the C-store, round-trip the X tile through LDS,
// MFMA with Wta (staged into Ws), then sum tanh(u)*proj into attsum[job].
struct GJob {
    const void* A;
    const short* Wt;
    const float* av;
    void* C;
    float* fs;
    float* fd;
    int M;
};

template <typename AT, int K, int KPAD, int N, int CSTORE, bool DO_F, bool DO_ATT2>
__global__ __launch_bounds__(256) void mfma_gemm(GJob j0, GJob j1, int nb0,
                                                 float* __restrict__ attsum,
                                                 const short* __restrict__ WtaP) {
    constexpr int NT = N / 16;
    constexpr int NP = KPAD / 64;
    int t = threadIdx.x;

    __shared__ short As[64 * 72];
    __shared__ short Ws[N * 72];
    __shared__ float red[8];
    int lane = t & 63;
    int wid = t >> 6;
    int col = lane & 15;
    int quad = lane >> 4;

    int bid = blockIdx.x;
    bool sec = bid >= nb0;
    GJob J = sec ? j1 : j0;
    const AT* A = (const AT*)J.A;
    const short* Wt = J.Wt;
    const float* av = J.av;
    int M = J.M;
    int row0 = (sec ? bid - nb0 : bid) * 64;

    f4v acc[NT];
#pragma unroll
    for (int i = 0; i < NT; ++i) { f4v z = {0.f, 0.f, 0.f, 0.f}; acc[i] = z; }

    // register staging buffers (unused ones are DCE'd per instantiation)
    float4 ra[4];
    s8v rsa[2];
    s8v rb[NT / 2];

    auto issue = [&](int p) {   // issue global loads for phase p into registers
        int k0 = p * 64;
        if constexpr (sizeof(AT) == 4) {
            const float4* A4 = (const float4*)A;
            int f = t & 15, r0 = t >> 4;
#pragma unroll
            for (int r = 0; r < 4; ++r) {
                int gr = row0 + r0 + 16 * r;
                int f4i = (k0 >> 2) + f;
                float4 v = {0.f, 0.f, 0.f, 0.f};
                if (gr < M && f4i < K / 4) v = A4[(size_t)gr * (K / 4) + f4i];
                ra[r] = v;
            }
        } else {
            int c8 = t & 7, r0 = t >> 3;
#pragma unroll
            for (int r = 0; r < 2; ++r) {
                int gr = row0 + r0 + 32 * r;
                s8v v = {0, 0, 0, 0, 0, 0, 0, 0};
                if (gr < M) v = *(const s8v*)&A[(size_t)gr * K + k0 + c8 * 8];
                rsa[r] = v;
            }
        }
        {
            int c8 = t & 7, r0 = t >> 3;
#pragma unroll
            for (int r = 0; r < NT / 2; ++r)
                rb[r] = *(const s8v*)&Wt[(size_t)(r0 + 32 * r) * KPAD + k0 + c8 * 8];
        }
    };
    auto commit = [&]() {   // registers -> LDS (implicit vmcnt wait lands here)
        if constexpr (sizeof(AT) == 4) {
            int f = t & 15, r0 = t >> 4;
#pragma unroll
            for (int r = 0; r < 4; ++r) {
                float4 v = ra[r];
                s4v sv = {f2bf(v.x), f2bf(v.y), f2bf(v.z), f2bf(v.w)};
                *(s4v*)&As[(r0 + 16 * r) * 72 + f * 4] = sv;
            }
        } else {
            int c8 = t & 7, r0 = t >> 3;
#pragma unroll
            for (int r = 0; r < 2; ++r) *(s8v*)&As[(r0 + 32 * r) * 72 + c8 * 8] = rsa[r];
        }
        int c8 = t & 7, r0 = t >> 3;
#pragma unroll
        for (int r = 0; r < NT / 2; ++r) *(s8v*)&Ws[(r0 + 32 * r) * 72 + c8 * 8] = rb[r];
    };

    issue(0);
    for (int p = 0; p < NP; ++p) {
        __syncthreads();            // previous phase's LDS reads complete
        commit();
        __syncthreads();
        if (p + 1 < NP) issue(p + 1);   // overlap next-phase HBM latency with compute
#pragma unroll
        for (int c2 = 0; c2 < 2; ++c2) {
            int ko = c2 * 32 + quad * 8;
            bf8v af = *(const bf8v*)&As[(wid * 16 + col) * 72 + ko];
#pragma unroll
            for (int nt = 0; nt < NT; ++nt) {
                bf8v bf = *(const bf8v*)&Ws[(nt * 16 + col) * 72 + ko];
                acc[nt] = __builtin_amdgcn_mfma_f32_16x16x32_bf16(af, bf, acc[nt], 0, 0, 0);
            }
        }
    }

    int mbase = row0 + wid * 16;
    if constexpr (CSTORE == 1) {
        float* C = (float*)J.C;
#pragma unroll
        for (int nt = 0; nt < NT; ++nt)
#pragma unroll
            for (int r = 0; r < 4; ++r) {
                int gr = mbase + quad * 4 + r;
                if (gr < M) C[(size_t)gr * N + nt * 16 + col] = acc[nt][r];
            }
    } else if constexpr (CSTORE == 2 || CSTORE == 3) {
        short* C = (short*)J.C;
#pragma unroll
        for (int nt = 0; nt < NT; ++nt)
#pragma unroll
            for (int r = 0; r < 4; ++r) {
                int gr = mbase + quad * 4 + r;
                float v = acc[nt][r];
                if constexpr (CSTORE == 3) { v = felu(v); acc[nt][r] = v; }
                if (gr < M) C[(size_t)gr * N + nt * 16 + col] = f2bf(v);
            }
    }
    if constexpr (DO_F) {
        if (av) {   // runtime guard: job may not need the f_src/f_dst epilogue
            float* fs = J.fs;
            float* fd = J.fd;
            float a0[NT], a1[NT];
#pragma unroll
            for (int nt = 0; nt < NT; ++nt) {
                a0[nt] = av[nt * 16 + col];
                a1[nt] = av[N + nt * 16 + col];
            }
#pragma unroll
            for (int r = 0; r < 4; ++r) {
                float p0 = 0.f, p1 = 0.f;
#pragma unroll
                for (int nt = 0; nt < NT; ++nt) {
                    p0 += acc[nt][r] * a0[nt];
                    p1 += acc[nt][r] * a1[nt];
                }
#pragma unroll
                for (int o = 8; o > 0; o >>= 1) {
                    p0 += __shfl_xor(p0, o, 64);
                    p1 += __shfl_xor(p1, o, 64);
                }
                int gr = mbase + quad * 4 + r;
                if (col == 0 && gr < M) { fs[gr] = p0; fd[gr] = p1; }
            }
        }
    }
    if constexpr (DO_ATT2) {
        static_assert(!DO_ATT2 || N == 128, "fused att expects N=128");
        f4v satt[NT];
#pragma unroll
        for (int i = 0; i < NT; ++i) { f4v z = {0.f, 0.f, 0.f, 0.f}; satt[i] = z; }
#pragma unroll
        for (int h = 0; h < 2; ++h) {
            __syncthreads();   // all waves done with As/Ws (main loop or previous half)
            // stage X-tile cols [h*64, h*64+64) into As (bf16, elu'd acc; rows>=M are 0)
#pragma unroll
            for (int nt2 = 0; nt2 < 4; ++nt2) {
#pragma unroll
                for (int r = 0; r < 4; ++r)
                    As[(wid * 16 + quad * 4 + r) * 72 + nt2 * 16 + col] =
                        f2bf(acc[h * 4 + nt2][r]);
            }
            // stage Wta k-half into Ws: Ws[n][kk] = Wta[n*128 + h*64 + kk]
            {
                int c8 = t & 7, r0 = t >> 3;
#pragma unroll
                for (int r = 0; r < 4; ++r)
                    *(s8v*)&Ws[(r0 + 32 * r) * 72 + c8 * 8] =
                        *(const s8v*)&WtaP[(size_t)(r0 + 32 * r) * 128 + h * 64 + c8 * 8];
            }
            __syncthreads();
#pragma unroll
            for (int c2 = 0; c2 < 2; ++c2) {
                int ko = c2 * 32 + quad * 8;
                bf8v af = *(const bf8v*)&As[(wid * 16 + col) * 72 + ko];
#pragma unroll
                for (int nt = 0; nt < NT; ++nt) {
                    bf8v bf = *(const bf8v*)&Ws[(nt * 16 + col) * 72 + ko];
                    satt[nt] = __builtin_amdgcn_mfma_f32_16x16x32_bf16(af, bf, satt[nt], 0, 0, 0);
                }
            }
        }
        float s = 0.f;
#pragma unroll
        for (int nt = 0; nt < NT; ++nt) {
            float pj = av[nt * 16 + col];   // av = weight_proj for ATT2 jobs
#pragma unroll
            for (int r = 0; r < 4; ++r) s += tanhf(satt[nt][r]) * pj;
        }
        s = waveReduce(s);
        if (lane == 0) red[wid] = s;
        __syncthreads();
        if (t == 0) atomicAdd(attsum + (sec ? 1 : 0), red[0] + red[1] + red[2] + red[3]);
    }
}

// h[i,:] = mean_16 P[idx[i,j],:] (P bf16, row = 32 uint32) -> H bf16; fused fs/fd.
// half-wave per source row, uint32 (2 cols) per lane.
__global__ void gather_h64(const int* __restrict__ idx, const uint32* __restrict__ P,
                           const float* __restrict__ a,
                           short* __restrict__ H, float* __restrict__ fsv, float* __restrict__ fdv,
                           int N) {
    int wv = (blockIdx.x * blockDim.x + threadIdx.x) >> 6;
    int lane = threadIdx.x & 63;
    if (wv >= N) return;
    int hf = lane >> 5, li = lane & 31;
    const int* ip = idx + wv * 16;
    float a0 = 0.f, a1 = 0.f;
#pragma unroll
    for (int u = 0; u < 8; ++u) {
        int ind = ip[2 * u + hf];
        uint32 d = P[(size_t)ind * 32 + li];
        a0 += blo(d);
        a1 += bhi(d);
    }
    a0 += __shfl_xor(a0, 32, 64);
    a1 += __shfl_xor(a1, 32, 64);
    a0 *= 0.0625f;
    a1 *= 0.0625f;
    if (hf == 0) ((uint32*)H)[(size_t)wv * 32 + li] = pack2(a0, a1);
    float cp = hf ? 0.f : (a0 * a[2 * li] + a1 * a[2 * li + 1]);
    float cq = hf ? 0.f : (a0 * a[64 + 2 * li] + a1 * a[64 + 2 * li + 1]);
    float p = waveReduce(cp);
    float q = waveReduce(cq);
    if (lane == 0) { fsv[wv] = p; fdv[wv] = q; }
}

// ---------------- fused edge-weight + 64-dim bucket aggregation (both GAT layers) ----------------
// Lane l precomputes (c,e) for bucket slot l; accumulation gathers 128B rows quarter-wave x uint2.
// ELU: apply elu to output (layer 1). F2: fused fs2/fd2 = out . (W2^T a2) epilogue (layer 1 only;
// valid because f_src(layer2) = (x1 W2).a = x1.(W2^T a) -- aggregation/projection commute).
template <bool ELU, bool F2>
__global__ void agg64t_kernel(const int* __restrict__ cursor, const int* __restrict__ ecol,
                              const float* __restrict__ fs, const float* __restrict__ fd,
                              const uint32* __restrict__ hb, uint32* __restrict__ out,
                              const float* __restrict__ vab,
                              float* __restrict__ fs2, float* __restrict__ fd2,
                              int N2, int NTW) {
    int wv = (blockIdx.x * blockDim.x + threadIdx.x) >> 6;
    int lane = threadIdx.x & 63;
    if (wv >= N2) return;
    int s = wv << CAPSH;
    int ne = min(cursor[wv] - s, CAP);
    int coff = wv < NTW ? 0 : NTW;
    float fsr = fs[wv];
    int cl = 0;
    float el = 0.f;
    if (lane < ne) {
        cl = ecol[s + lane];
        float f = fsr + fd[coff + cl];
        el = __expf(-(f >= 0.f ? f : 0.2f * f));
    }
    int qd = lane >> 4, li = lane & 15;
    const uint2* h2 = (const uint2*)hb;   // row = 16 uint2 (64 bf16)
    float a0 = 0.f, a1 = 0.f, a2 = 0.f, a3 = 0.f, den = 0.f;
    for (int kb = 0; kb < ne; kb += 16) {
        int k0 = kb + qd, k1 = kb + 4 + qd, k2 = kb + 8 + qd, k3 = kb + 12 + qd;  // all < 64
        int c0 = __shfl(cl, k0, 64); float e0 = __shfl(el, k0, 64);
        int c1 = __shfl(cl, k1, 64); float e1 = __shfl(el, k1, 64);
        int c2 = __shfl(cl, k2, 64); float e2 = __shfl(el, k2, 64);
        int c3 = __shfl(cl, k3, 64); float e3 = __shfl(el, k3, 64);
        uint2 d0 = h2[(size_t)(coff + c0) * 16 + li];
        uint2 d1 = h2[(size_t)(coff + c1) * 16 + li];
        uint2 d2 = h2[(size_t)(coff + c2) * 16 + li];
        uint2 d3 = h2[(size_t)(coff + c3) * 16 + li];
        a0 += e0 * blo(d0.x) + e1 * blo(d1.x) + e2 * blo(d2.x) + e3 * blo(d3.x);
        a1 += e0 * bhi(d0.x) + e1 * bhi(d1.x) + e2 * bhi(d2.x) + e3 * bhi(d3.x);
        a2 += e0 * blo(d0.y) + e1 * blo(d1.y) + e2 * blo(d2.y) + e3 * blo(d3.y);
        a3 += e0 * bhi(d0.y) + e1 * bhi(d1.y) + e2 * bhi(d2.y) + e3 * bhi(d3.y);
        den += e0 + e1 + e2 + e3;
    }
    a0 += __shfl_xor(a0, 16, 64); a0 += __shfl_xor(a0, 32, 64);
    a1 += __shfl_xor(a1, 16, 64); a1 += __shfl_xor(a1, 32, 64);
    a2 += __shfl_xor(a2, 16, 64); a2 += __shfl_xor(a2, 32, 64);
    a3 += __shfl_xor(a3, 16, 64); a3 += __shfl_xor(a3, 32, 64);
    den += __shfl_xor(den, 16, 64); den += __shfl_xor(den, 32, 64);
    // all lanes now hold the totals for their column group li = lane&15
    float inv = 1.f / (den + 1e-16f);
    float v0 = a0 * inv, v1 = a1 * inv, v2 = a2 * inv, v3 = a3 * inv;
    if constexpr (ELU) {
        v0 = felu(v0); v1 = felu(v1); v2 = felu(v2); v3 = felu(v3);
    }
    if (lane < 16) {
        uint2 o = {pack2(v0, v1), pack2(v2, v3)};
        ((uint2*)out)[(size_t)wv * 16 + li] = o;
    }
    if constexpr (F2) {
        const float* vv = vab + (wv < NTW ? 0 : 128);
        float ps = 0.f, pd = 0.f;
        if (lane < 16) {
            ps = v0 * vv[4 * li] + v1 * vv[4 * li + 1] + v2 * vv[4 * li + 2] + v3 * vv[4 * li + 3];
            pd = v0 * vv[64 + 4 * li] + v1 * vv[64 + 4 * li + 1] +
                 v2 * vv[64 + 4 * li + 2] + v3 * vv[64 + 4 * li + 3];
        }
        ps = waveReduce(ps);
        pd = waveReduce(pd);
        if (lane == 0) { fs2[wv] = ps; fd2[wv] = pd; }
    }
}

// ---------------- output (bf16 X inputs) ----------------
__global__ void final_kernel(const short* __restrict__ twX, const short* __restrict__ tuX,
                             const int* __restrict__ twi, const int* __restrict__ tui,
                             const float* __restrict__ attsum,
                             const float* __restrict__ outW, const float* __restrict__ outb,
                             float* __restrict__ out, int B, float invNtw, float invNuv) {
    int wave = (blockIdx.x * blockDim.x + threadIdx.x) >> 6;
    int lane = threadIdx.x & 63;
    if (wave >= B) return;
    float z0 = attsum[0] * invNtw, z1 = attsum[1] * invNuv;
    float m = fmaxf(z0, z1);
    float e0 = expf(z0 - m), e1 = expf(z1 - m);
    float a0 = e0 / (e0 + e1), a1 = e1 / (e0 + e1);
    int ti = twi[wave], ui = tui[wave];
    float l0 = 0.f, l1 = 0.f;
#pragma unroll
    for (int p = 0; p < 2; ++p) {
        int j = lane + 64 * p;
        float feat = a0 * bf2f(twX[(size_t)ti * 128 + j]) + a1 * bf2f(tuX[(size_t)ui * 128 + j]);
        l0 += feat * outW[j];
        l1 += feat * outW[128 + j];
    }
    l0 = waveReduce(l0);
    l1 = waveReduce(l1);
    if (lane == 0) {
        l0 += outb[0];
        l1 += outb[1];
        float mm = fmaxf(l0, l1);
        float lse = mm + logf(expf(l0 - mm) + expf(l1 - mm));
        out[wave * 2 + 0] = l0 - lse;
        out[wave * 2 + 1] = l1 - lse;
    }
}

extern "C" void kernel_launch(void* const* d_in, const int* in_sizes, int n_in,
                              void* d_out, int out_size, void* d_ws, size_t ws_size,
                              hipStream_t stream) {
    const int* features_index = (const int*)d_in[0];
    const int* tw_edges = (const int*)d_in[1];
    const int* ut_edges = (const int*)d_in[2];
    const int* tw_gidx = (const int*)d_in[3];
    const int* ut_gidx = (const int*)d_in[4];
    const float* word_emb = (const float*)d_in[5];
    const float* user_emb = (const float*)d_in[6];
    const float* tw_W1 = (const float*)d_in[7];
    const float* tw_a1 = (const float*)d_in[8];
    const float* tw_W2 = (const float*)d_in[9];
    const float* tw_a2 = (const float*)d_in[10];
    const float* tu_W1 = (const float*)d_in[11];
    const float* tu_a1 = (const float*)d_in[12];
    const float* tu_W2 = (const float*)d_in[13];
    const float* tu_a2 = (const float*)d_in[14];
    const float* weight_W = (const float*)d_in[15];
    const float* weight_proj = (const float*)d_in[16];
    const float* out_W = (const float*)d_in[17];
    const float* out_b = (const float*)d_in[18];

    const int E = in_sizes[1] / 2;              // 800000
    const int NTW = in_sizes[0] / 16;           // 50000
    const int VOCAB = in_sizes[5] / 300;        // 50000
    const int UV = in_sizes[6] / 300;           // 50000
    const int B = in_sizes[3];                  // 4096
    const int N2 = NTW + UV;
    const bool packOK = (NTW < 65536) && (UV < 65536);

    char* ws = (char*)d_ws;
    size_t off = 0;
    auto carve = [&](size_t bytes) -> void* {
        void* p = ws + off;
        off += (bytes + 255) & ~(size_t)255;
        return p;
    };
    float* Pbuf = (float*)carve((size_t)VOCAB * 64 * sizeof(float));     // 12.8 MB region (bf16 P)
    short* Hb1 = (short*)carve((size_t)N2 * 64 * sizeof(short));         // layer-1 h, both graphs
    short* Y = (short*)carve((size_t)N2 * 64 * sizeof(short));           // layer-2 aggregated x1 (pre-GEMM)
    short* X = (short*)carve((size_t)N2 * 128 * sizeof(short));          // final features
    float* f_s = (float*)carve((size_t)N2 * sizeof(float));
    float* f_d = (float*)carve((size_t)N2 * sizeof(float));
    float* f_s2 = (float*)carve((size_t)N2 * sizeof(float));
    float* f_d2 = (float*)carve((size_t)N2 * sizeof(float));
    float* attsum = (float*)carve(256);
    float* vab = (float*)carve(256 * sizeof(float));
    int* cursor = (int*)carve((size_t)N2 * sizeof(int));
    int* ecol = (int*)carve((size_t)N2 * CAP * sizeof(int));             // 25.6 MB buckets
    uint32* epkA = (uint32*)carve((size_t)E * sizeof(uint32));           // packed tweet edges
    uint32* epkB = (uint32*)carve((size_t)E * sizeof(uint32));           // packed user edges
    short* Wt1tw = (short*)carve((size_t)64 * 320 * sizeof(short));
    short* Wt1tu = (short*)carve((size_t)64 * 320 * sizeof(short));
    short* Wt2tw = (short*)carve((size_t)128 * 64 * sizeof(short));
    short* Wt2tu = (short*)carve((size_t)128 * 64 * sizeof(short));
    short* Wta   = (short*)carve((size_t)128 * 128 * sizeof(short));
    // num1 (N2*64 bf16 = 12.8 MB) aliases the Pbuf region: P's last read (gather_h64)
    // precedes the agg64 write on the same stream.
    short* num1 = ((size_t)VOCAB * 64 * sizeof(float) >= (size_t)N2 * 64 * sizeof(short))
                      ? (short*)Pbuf
                      : (short*)carve((size_t)N2 * 64 * sizeof(short));
    (void)ws_size; (void)n_in; (void)out_size;

    // ---- weight transposes + cursor init + attsum clear + vab + edge prepack (one launch) ----
    WJobs jb;
    jb.src[0] = tw_W1;    jb.dst[0] = Wt1tw; jb.K[0] = 300; jb.N[0] = 64;  jb.KP[0] = 320; jb.total[0] = 64 * 320;
    jb.src[1] = tu_W1;    jb.dst[1] = Wt1tu; jb.K[1] = 300; jb.N[1] = 64;  jb.KP[1] = 320; jb.total[1] = 64 * 320;
    jb.src[2] = tw_W2;    jb.dst[2] = Wt2tw; jb.K[2] = 64;  jb.N[2] = 128; jb.KP[2] = 64;  jb.total[2] = 128 * 64;
    jb.src[3] = tu_W2;    jb.dst[3] = Wt2tu; jb.K[3] = 64;  jb.N[3] = 128; jb.KP[3] = 64;  jb.total[3] = 128 * 64;
    jb.src[4] = weight_W; jb.dst[4] = Wta;   jb.K[4] = 128; jb.N[4] = 128; jb.KP[4] = 128; jb.total[4] = 128 * 128;
    jb.cursor = cursor;
    jb.attsum = attsum;
    jb.vab = vab;
    jb.W2tw = tw_W2; jb.a2tw = tw_a2;
    jb.W2tu = tu_W2; jb.a2tu = tu_a2;
    jb.N2 = N2;
    jb.rowA = tw_edges; jb.colA = tw_edges + E;
    jb.rowB = ut_edges; jb.colB = ut_edges + E;
    jb.epkA = packOK ? epkA : nullptr;
    jb.epkB = packOK ? epkB : nullptr;
    jb.E = E;
    {
        int gx = (64 * 320 + 255) / 256;
        int gc = (N2 + 255) / 256;
        int ge = packOK ? (E + 255) / 256 : 0;
        if (gc > gx) gx = gc;
        if (ge > gx) gx = ge;
        dim3 g(gx, 8);
        wtrans_all<<<g, 256, 0, stream>>>(jb);
    }

    // ---- XCD-windowed CSR scatter (packed: 4 windows/graph, quartered read volume) ----
    if (packOK) {
        int nchunk = (E + 255) / 256;
        int Wt = (NTW + 3) / 4, Wu = (UV + 3) / 4;
        scatter8p_kernel<<<8 * nchunk, 256, 0, stream>>>(epkA, epkB, cursor, ecol,
                                                         E, NTW, UV, Wt, Wu);
    } else {
        int nchunk = (2 * E + 255) / 256;
        int Wsize = (N2 + 7) / 8;
        scatter8_kernel<<<8 * nchunk, 256, 0, stream>>>(tw_edges, tw_edges + E,
                                                        ut_edges, ut_edges + E,
                                                        cursor, ecol, E, NTW, Wsize);
    }

    // ---- layer-1 projections: both branches in one dual-job launch ----
    {
        GJob a{word_emb, Wt1tw, nullptr, Pbuf, nullptr, nullptr, VOCAB};
        GJob b{user_emb, Wt1tu, tu_a1, Hb1 + (size_t)NTW * 64, f_s + NTW, f_d + NTW, UV};
        int nbw = (VOCAB + 63) / 64, nbu = (UV + 63) / 64;
        mfma_gemm<float, 300, 320, 64, 2, true, false><<<nbw + nbu, 256, 0, stream>>>(
            a, b, nbw, nullptr, nullptr);
    }
    gather_h64<<<(NTW + 3) / 4, 256, 0, stream>>>(features_index, (const uint32*)Pbuf, tw_a1,
                                                  Hb1, f_s, f_d, NTW);

    // ---- layer-1 aggregation (elu) + fused layer-2 fs/fd epilogue ----
    agg64t_kernel<true, true><<<(N2 + 3) / 4, 256, 0, stream>>>(
        cursor, ecol, f_s, f_d, (const uint32*)Hb1, (uint32*)num1, vab, f_s2, f_d2, N2, NTW);

    // ---- layer-2 aggregation over 64-dim x1 (aggregation/projection commute) ----
    agg64t_kernel<false, false><<<(N2 + 3) / 4, 256, 0, stream>>>(
        cursor, ecol, f_s2, f_d2, (const uint32*)num1, (uint32*)Y, nullptr, nullptr, nullptr,
        N2, NTW);

    // ---- layer-2 GEMM: X = elu(Y @ W2) with FUSED attention reduce (X@Wta, tanh, proj) ----
    {
        int nbtw = (NTW + 63) / 64, nbtu = (UV + 63) / 64;
        GJob a{Y, Wt2tw, weight_proj, X, nullptr, nullptr, NTW};
        GJob b{Y + (size_t)NTW * 64, Wt2tu, weight_proj, X + (size_t)NTW * 128,
               nullptr, nullptr, UV};
        mfma_gemm<short, 64, 64, 128, 3, false, true><<<nbtw + nbtu, 256, 0, stream>>>(
            a, b, nbtw, attsum, Wta);
    }

    final_kernel<<<(B + 3) / 4, 256, 0, stream>>>(X, X + (size_t)NTW * 128, tw_gidx, ut_gidx,
                                                  attsum, out_W, out_b, (float*)d_out, B,
                                                  1.0f / (float)NTW, 1.0f / (float)UV);
}

// Round 11
// 407.863 us; speedup vs baseline: 1.0192x; 1.0192x over previous
//
#include <hip/hip_runtime.h>
#include <hip/hip_bf16.h>

typedef __hip_bfloat16 bf16;
typedef unsigned int uint32;
typedef __attribute__((ext_vector_type(8))) short s8v;   // 8 bf16 (16B)
typedef __attribute__((ext_vector_type(4))) short s4v;   // 4 bf16 (8B)
typedef __attribute__((ext_vector_type(8))) short bf8v;  // MFMA A/B frag
typedef __attribute__((ext_vector_type(4))) float f4v;   // MFMA accumulator

#define CAP 64          // bucket capacity per destination row (deg ~ Poisson(16); P(>64) ~ 1e-20)
#define CAPSH 6

__device__ __forceinline__ float waveReduce(float v) {
#pragma unroll
    for (int o = 32; o > 0; o >>= 1) v += __shfl_xor(v, o, 64);
    return v;
}

__device__ __forceinline__ short f2bf(float x) {
    __hip_bfloat16 h = __float2bfloat16(x);
    return *reinterpret_cast<short*>(&h);
}
__device__ __forceinline__ float bf2f(short s) {
    return __uint_as_float(((uint32)(unsigned short)s) << 16);
}
__device__ __forceinline__ uint32 pack2(float x, float y) {
    return (uint32)(unsigned short)f2bf(x) | (((uint32)(unsigned short)f2bf(y)) << 16);
}
__device__ __forceinline__ float blo(uint32 d) { return __uint_as_float(d << 16); }
__device__ __forceinline__ float bhi(uint32 d) { return __uint_as_float(d & 0xffff0000u); }
// fast ELU: expm1f library call -> native v_exp_f32 path (error << bf16 rounding)
__device__ __forceinline__ float felu(float x) { return x > 0.f ? x : __expf(x) - 1.f; }

// ------- batched weight transpose + cursor init + attsum clear + vab + edge prepack -------
struct WJobs {
    const float* src[5];
    short* dst[5];
    int K[5], N[5], KP[5], total[5];
    int* cursor;
    float* attsum;
    float* vab;           // [256]: tw{src,dst} then tu{src,dst}, 64 floats each
    const float* W2tw; const float* a2tw;
    const float* W2tu; const float* a2tu;
    int N2;
    // edge prepack (rows/cols < 65536 -> one uint32 per edge)
    const int* rowA; const int* colA;
    const int* rowB; const int* colB;
    uint32* epkA; uint32* epkB;
    int E;
};
__global__ void wtrans_all(WJobs jb) {
    int j = blockIdx.y;
    int i = blockIdx.x * blockDim.x + threadIdx.x;
    if (j == 5) {   // aux: cursor init + attsum clear + vab = W2^T a2
        if (i < jb.N2) jb.cursor[i] = i << CAPSH;
        if (i < 2) jb.attsum[i] = 0.f;
        if (i < 256) {
            int br = i >> 7;          // 0=tw 1=tu
            int half = (i >> 6) & 1;  // 0=src 1=dst
            int k = i & 63;
            const float* W2 = br ? jb.W2tu : jb.W2tw;   // [64][128] row-major
            const float* a2 = br ? jb.a2tu : jb.a2tw;   // [256]
            float s = 0.f;
#pragma unroll 4
            for (int q = 0; q < 128; ++q) s += W2[k * 128 + q] * a2[half * 128 + q];
            jb.vab[i] = s;
        }
        return;
    }
    if (j == 6) {   // prepack tweet edges
        if (jb.epkA && i < jb.E)
            jb.epkA[i] = ((uint32)jb.rowA[i] << 16) | (uint32)jb.colA[i];
        return;
    }
    if (j == 7) {   // prepack user edges
        if (jb.epkB && i < jb.E)
            jb.epkB[i] = ((uint32)jb.rowB[i] << 16) | (uint32)jb.colB[i];
        return;
    }
    if (i >= jb.total[j]) return;
    int KP = jb.KP[j];
    int n = i / KP, k = i - n * KP;
    jb.dst[j][i] = f2bf(k < jb.K[j] ? jb.src[j][(size_t)k * jb.N[j] + n] : 0.f);
}

// fallback standalone scatter (raw row/col) for sizes >= 65536 — R9 behavior
__global__ void scatter8_kernel(const int* __restrict__ rowA, const int* __restrict__ colA,
                                const int* __restrict__ rowB, const int* __restrict__ colB,
                                int* __restrict__ cursor, int* __restrict__ ecol,
                                int E, int NTW, int Wsize) {
    int w = (int)blockIdx.x & 7;
    int i = ((int)blockIdx.x >> 3) * 256 + (int)threadIdx.x;
    int lo = w * Wsize, hi = lo + Wsize;
    int r = -1, c = 0;
    if (i < E) {
        r = __builtin_nontemporal_load(rowA + i);
        c = __builtin_nontemporal_load(colA + i);
    } else if (i < 2 * E) {
        r = NTW + __builtin_nontemporal_load(rowB + (i - E));
        c = __builtin_nontemporal_load(colB + (i - E));
    }
    if (r >= lo && r < hi) {
        int p0 = atomicAdd(&cursor[r], 1);
        if (p0 < (r << CAPSH) + CAP) ecol[p0] = c;
    }
}

// ---------------- universal MFMA GEMM (2-job block-range dispatch + packed scatter tail) ----------------
// CSTORE: 0=none, 1=f32, 2=bf16, 3=bf16 with fused ELU
// DO_ATT2: fused attention reduce — after the C-store, round-trip the X tile through LDS,
// MFMA with Wta (staged into Ws), then sum tanh(u)*proj into attsum[job].
// DO_SCAT: packed XCD-windowed scatter tail. w = absolute blockIdx&7 (round-robin XCD match):
// each XCD fills only its own 3.2MB bucket slice; scatter waves are latency-parked and
// complementary to the GEMM's MFMA/VALU waves (R7 A/B: fusion >= serial even with 4x the
// read pollution; packed edges quarter it).
struct GJob {
    const void* A;
    const short* Wt;
    const float* av;
    void* C;
    float* fs;
    float* fd;
    int M;
};
struct SJob {
    const uint32* epkA; const uint32* epkB;
    int* cursor; int* ecol;
    int E; int NTW; int UV; int Wt; int Wu; int nbg;
};

template <typename AT, int K, int KPAD, int N, int CSTORE, bool DO_F, bool DO_ATT2, bool DO_SCAT>
__global__ __launch_bounds__(256) void mfma_gemm(GJob j0, GJob j1, int nb0,
                                                 float* __restrict__ attsum,
                                                 const short* __restrict__ WtaP, SJob sj) {
    constexpr int NT = N / 16;
    constexpr int NP = KPAD / 64;
    int t = threadIdx.x;

    if constexpr (DO_SCAT) {
        if ((int)blockIdx.x >= sj.nbg) {
            int w = (int)blockIdx.x & 7;   // absolute -> XCD-aligned window
            int i = (((int)blockIdx.x - sj.nbg) >> 3) * 256 + t;
            if (i < sj.E) {
                if (w < 4) {
                    uint32 pk = __builtin_nontemporal_load(sj.epkA + i);
                    int r = (int)(pk >> 16);
                    int lo = w * sj.Wt;
                    int hi = lo + sj.Wt; if (hi > sj.NTW) hi = sj.NTW;
                    if (r >= lo && r < hi) {
                        int p0 = atomicAdd(&sj.cursor[r], 1);
                        if (p0 < (r << CAPSH) + CAP) sj.ecol[p0] = (int)(pk & 0xffffu);
                    }
                } else {
                    uint32 pk = __builtin_nontemporal_load(sj.epkB + i);
                    int r = (int)(pk >> 16);
                    int lo = (w - 4) * sj.Wu;
                    int hi = lo + sj.Wu; if (hi > sj.UV) hi = sj.UV;
                    if (r >= lo && r < hi) {
                        int rg = sj.NTW + r;
                        int p0 = atomicAdd(&sj.cursor[rg], 1);
                        if (p0 < (rg << CAPSH) + CAP) sj.ecol[p0] = (int)(pk & 0xffffu);
                    }
                }
            }
            return;
        }
    }

    __shared__ short As[64 * 72];
    __shared__ short Ws[N * 72];
    __shared__ float red[8];
    int lane = t & 63;
    int wid = t >> 6;
    int col = lane & 15;
    int quad = lane >> 4;

    int bid = blockIdx.x;
    bool sec = bid >= nb0;
    GJob J = sec ? j1 : j0;
    const AT* A = (const AT*)J.A;
    const short* Wt = J.Wt;
    const float* av = J.av;
    int M = J.M;
    int row0 = (sec ? bid - nb0 : bid) * 64;

    f4v acc[NT];
#pragma unroll
    for (int i = 0; i < NT; ++i) { f4v z = {0.f, 0.f, 0.f, 0.f}; acc[i] = z; }

    // register staging buffers (unused ones are DCE'd per instantiation)
    float4 ra[4];
    s8v rsa[2];
    s8v rb[NT / 2];

    auto issue = [&](int p) {   // issue global loads for phase p into registers
        int k0 = p * 64;
        if constexpr (sizeof(AT) == 4) {
            const float4* A4 = (const float4*)A;
            int f = t & 15, r0 = t >> 4;
#pragma unroll
            for (int r = 0; r < 4; ++r) {
                int gr = row0 + r0 + 16 * r;
                int f4i = (k0 >> 2) + f;
                float4 v = {0.f, 0.f, 0.f, 0.f};
                if (gr < M && f4i < K / 4) v = A4[(size_t)gr * (K / 4) + f4i];
                ra[r] = v;
            }
        } else {
            int c8 = t & 7, r0 = t >> 3;
#pragma unroll
            for (int r = 0; r < 2; ++r) {
                int gr = row0 + r0 + 32 * r;
                s8v v = {0, 0, 0, 0, 0, 0, 0, 0};
                if (gr < M) v = *(const s8v*)&A[(size_t)gr * K + k0 + c8 * 8];
                rsa[r] = v;
            }
        }
        {
            int c8 = t & 7, r0 = t >> 3;
#pragma unroll
            for (int r = 0; r < NT / 2; ++r)
                rb[r] = *(const s8v*)&Wt[(size_t)(r0 + 32 * r) * KPAD + k0 + c8 * 8];
        }
    };
    auto commit = [&]() {   // registers -> LDS (implicit vmcnt wait lands here)
        if constexpr (sizeof(AT) == 4) {
            int f = t & 15, r0 = t >> 4;
#pragma unroll
            for (int r = 0; r < 4; ++r) {
                float4 v = ra[r];
                s4v sv = {f2bf(v.x), f2bf(v.y), f2bf(v.z), f2bf(v.w)};
                *(s4v*)&As[(r0 + 16 * r) * 72 + f * 4] = sv;
            }
        } else {
            int c8 = t & 7, r0 = t >> 3;
#pragma unroll
            for (int r = 0; r < 2; ++r) *(s8v*)&As[(r0 + 32 * r) * 72 + c8 * 8] = rsa[r];
        }
        int c8 = t & 7, r0 = t >> 3;
#pragma unroll
        for (int r = 0; r < NT / 2; ++r) *(s8v*)&Ws[(r0 + 32 * r) * 72 + c8 * 8] = rb[r];
    };

    issue(0);
    for (int p = 0; p < NP; ++p) {
        __syncthreads();            // previous phase's LDS reads complete
        commit();
        __syncthreads();
        if (p + 1 < NP) issue(p + 1);   // overlap next-phase HBM latency with compute
#pragma unroll
        for (int c2 = 0; c2 < 2; ++c2) {
            int ko = c2 * 32 + quad * 8;
            bf8v af = *(const bf8v*)&As[(wid * 16 + col) * 72 + ko];
#pragma unroll
            for (int nt = 0; nt < NT; ++nt) {
                bf8v bf = *(const bf8v*)&Ws[(nt * 16 + col) * 72 + ko];
                acc[nt] = __builtin_amdgcn_mfma_f32_16x16x32_bf16(af, bf, acc[nt], 0, 0, 0);
            }
        }
    }

    int mbase = row0 + wid * 16;
    if constexpr (CSTORE == 1) {
        float* C = (float*)J.C;
#pragma unroll
        for (int nt = 0; nt < NT; ++nt)
#pragma unroll
            for (int r = 0; r < 4; ++r) {
                int gr = mbase + quad * 4 + r;
                if (gr < M) C[(size_t)gr * N + nt * 16 + col] = acc[nt][r];
            }
    } else if constexpr (CSTORE == 2 || CSTORE == 3) {
        short* C = (short*)J.C;
#pragma unroll
        for (int nt = 0; nt < NT; ++nt)
#pragma unroll
            for (int r = 0; r < 4; ++r) {
                int gr = mbase + quad * 4 + r;
                float v = acc[nt][r];
                if constexpr (CSTORE == 3) { v = felu(v); acc[nt][r] = v; }
                if (gr < M) C[(size_t)gr * N + nt * 16 + col] = f2bf(v);
            }
    }
    if constexpr (DO_F) {
        if (av) {   // runtime guard: job may not need the f_src/f_dst epilogue
            float* fs = J.fs;
            float* fd = J.fd;
            float a0[NT], a1[NT];
#pragma unroll
            for (int nt = 0; nt < NT; ++nt) {
                a0[nt] = av[nt * 16 + col];
                a1[nt] = av[N + nt * 16 + col];
            }
#pragma unroll
            for (int r = 0; r < 4; ++r) {
                float p0 = 0.f, p1 = 0.f;
#pragma unroll
                for (int nt = 0; nt < NT; ++nt) {
                    p0 += acc[nt][r] * a0[nt];
                    p1 += acc[nt][r] * a1[nt];
                }
#pragma unroll
                for (int o = 8; o > 0; o >>= 1) {
                    p0 += __shfl_xor(p0, o, 64);
                    p1 += __shfl_xor(p1, o, 64);
                }
                int gr = mbase + quad * 4 + r;
                if (col == 0 && gr < M) { fs[gr] = p0; fd[gr] = p1; }
            }
        }
    }
    if constexpr (DO_ATT2) {
        static_assert(!DO_ATT2 || N == 128, "fused att expects N=128");
        f4v satt[NT];
#pragma unroll
        for (int i = 0; i < NT; ++i) { f4v z = {0.f, 0.f, 0.f, 0.f}; satt[i] = z; }
#pragma unroll
        for (int h = 0; h < 2; ++h) {
            __syncthreads();   // all waves done with As/Ws (main loop or previous half)
            // stage X-tile cols [h*64, h*64+64) into As (bf16, elu'd acc; rows>=M are 0)
#pragma unroll
            for (int nt2 = 0; nt2 < 4; ++nt2) {
#pragma unroll
                for (int r = 0; r < 4; ++r)
                    As[(wid * 16 + quad * 4 + r) * 72 + nt2 * 16 + col] =
                        f2bf(acc[h * 4 + nt2][r]);
            }
            // stage Wta k-half into Ws: Ws[n][kk] = Wta[n*128 + h*64 + kk]
            {
                int c8 = t & 7, r0 = t >> 3;
#pragma unroll
                for (int r = 0; r < 4; ++r)
                    *(s8v*)&Ws[(r0 + 32 * r) * 72 + c8 * 8] =
                        *(const s8v*)&WtaP[(size_t)(r0 + 32 * r) * 128 + h * 64 + c8 * 8];
            }
            __syncthreads();
#pragma unroll
            for (int c2 = 0; c2 < 2; ++c2) {
                int ko = c2 * 32 + quad * 8;
                bf8v af = *(const bf8v*)&As[(wid * 16 + col) * 72 + ko];
#pragma unroll
                for (int nt = 0; nt < NT; ++nt) {
                    bf8v bf = *(const bf8v*)&Ws[(nt * 16 + col) * 72 + ko];
                    satt[nt] = __builtin_amdgcn_mfma_f32_16x16x32_bf16(af, bf, satt[nt], 0, 0, 0);
                }
            }
        }
        float s = 0.f;
#pragma unroll
        for (int nt = 0; nt < NT; ++nt) {
            float pj = av[nt * 16 + col];   // av = weight_proj for ATT2 jobs
#pragma unroll
            for (int r = 0; r < 4; ++r) s += tanhf(satt[nt][r]) * pj;
        }
        s = waveReduce(s);
        if (lane == 0) red[wid] = s;
        __syncthreads();
        if (t == 0) atomicAdd(attsum + (sec ? 1 : 0), red[0] + red[1] + red[2] + red[3]);
    }
}

// h[i,:] = mean_16 P[idx[i,j],:] (P bf16, row = 32 uint32) -> H bf16; fused fs/fd.
// half-wave per source row, uint32 (2 cols) per lane.
__global__ void gather_h64(const int* __restrict__ idx, const uint32* __restrict__ P,
                           const float* __restrict__ a,
                           short* __restrict__ H, float* __restrict__ fsv, float* __restrict__ fdv,
                           int N) {
    int wv = (blockIdx.x * blockDim.x + threadIdx.x) >> 6;
    int lane = threadIdx.x & 63;
    if (wv >= N) return;
    int hf = lane >> 5, li = lane & 31;
    const int* ip = idx + wv * 16;
    float a0 = 0.f, a1 = 0.f;
#pragma unroll
    for (int u = 0; u < 8; ++u) {
        int ind = ip[2 * u + hf];
        uint32 d = P[(size_t)ind * 32 + li];
        a0 += blo(d);
        a1 += bhi(d);
    }
    a0 += __shfl_xor(a0, 32, 64);
    a1 += __shfl_xor(a1, 32, 64);
    a0 *= 0.0625f;
    a1 *= 0.0625f;
    if (hf == 0) ((uint32*)H)[(size_t)wv * 32 + li] = pack2(a0, a1);
    float cp = hf ? 0.f : (a0 * a[2 * li] + a1 * a[2 * li + 1]);
    float cq = hf ? 0.f : (a0 * a[64 + 2 * li] + a1 * a[64 + 2 * li + 1]);
    float p = waveReduce(cp);
    float q = waveReduce(cq);
    if (lane == 0) { fsv[wv] = p; fdv[wv] = q; }
}

// ---------------- fused edge-weight + 64-dim bucket aggregation (both GAT layers) ----------------
// Lane l precomputes (c,e) for bucket slot l; accumulation gathers 128B rows quarter-wave x uint2.
// ELU: apply elu to output (layer 1). F2: fused fs2/fd2 = out . (W2^T a2) epilogue (layer 1 only;
// valid because f_src(layer2) = (x1 W2).a = x1.(W2^T a) -- aggregation/projection commute).
template <bool ELU, bool F2>
__global__ void agg64t_kernel(const int* __restrict__ cursor, const int* __restrict__ ecol,
                              const float* __restrict__ fs, const float* __restrict__ fd,
                              const uint32* __restrict__ hb, uint32* __restrict__ out,
                              const float* __restrict__ vab,
                              float* __restrict__ fs2, float* __restrict__ fd2,
                              int N2, int NTW) {
    int wv = (blockIdx.x * blockDim.x + threadIdx.x) >> 6;
    int lane = threadIdx.x & 63;
    if (wv >= N2) return;
    int s = wv << CAPSH;
    int ne = min(cursor[wv] - s, CAP);
    int coff = wv < NTW ? 0 : NTW;
    float fsr = fs[wv];
    int cl = 0;
    float el = 0.f;
    if (lane < ne) {
        cl = ecol[s + lane];
        float f = fsr + fd[coff + cl];
        el = __expf(-(f >= 0.f ? f : 0.2f * f));
    }
    int qd = lane >> 4, li = lane & 15;
    const uint2* h2 = (const uint2*)hb;   // row = 16 uint2 (64 bf16)
    float a0 = 0.f, a1 = 0.f, a2 = 0.f, a3 = 0.f, den = 0.f;
    for (int kb = 0; kb < ne; kb += 16) {
        int k0 = kb + qd, k1 = kb + 4 + qd, k2 = kb + 8 + qd, k3 = kb + 12 + qd;  // all < 64
        int c0 = __shfl(cl, k0, 64); float e0 = __shfl(el, k0, 64);
        int c1 = __shfl(cl, k1, 64); float e1 = __shfl(el, k1, 64);
        int c2 = __shfl(cl, k2, 64); float e2 = __shfl(el, k2, 64);
        int c3 = __shfl(cl, k3, 64); float e3 = __shfl(el, k3, 64);
        uint2 d0 = h2[(size_t)(coff + c0) * 16 + li];
        uint2 d1 = h2[(size_t)(coff + c1) * 16 + li];
        uint2 d2 = h2[(size_t)(coff + c2) * 16 + li];
        uint2 d3 = h2[(size_t)(coff + c3) * 16 + li];
        a0 += e0 * blo(d0.x) + e1 * blo(d1.x) + e2 * blo(d2.x) + e3 * blo(d3.x);
        a1 += e0 * bhi(d0.x) + e1 * bhi(d1.x) + e2 * bhi(d2.x) + e3 * bhi(d3.x);
        a2 += e0 * blo(d0.y) + e1 * blo(d1.y) + e2 * blo(d2.y) + e3 * blo(d3.y);
        a3 += e0 * bhi(d0.y) + e1 * bhi(d1.y) + e2 * bhi(d2.y) + e3 * bhi(d3.y);
        den += e0 + e1 + e2 + e3;
    }
    a0 += __shfl_xor(a0, 16, 64); a0 += __shfl_xor(a0, 32, 64);
    a1 += __shfl_xor(a1, 16, 64); a1 += __shfl_xor(a1, 32, 64);
    a2 += __shfl_xor(a2, 16, 64); a2 += __shfl_xor(a2, 32, 64);
    a3 += __shfl_xor(a3, 16, 64); a3 += __shfl_xor(a3, 32, 64);
    den += __shfl_xor(den, 16, 64); den += __shfl_xor(den, 32, 64);
    // all lanes now hold the totals for their column group li = lane&15
    float inv = 1.f / (den + 1e-16f);
    float v0 = a0 * inv, v1 = a1 * inv, v2 = a2 * inv, v3 = a3 * inv;
    if constexpr (ELU) {
        v0 = felu(v0); v1 = felu(v1); v2 = felu(v2); v3 = felu(v3);
    }
    if (lane < 16) {
        uint2 o = {pack2(v0, v1), pack2(v2, v3)};
        ((uint2*)out)[(size_t)wv * 16 + li] = o;
    }
    if constexpr (F2) {
        const float* vv = vab + (wv < NTW ? 0 : 128);
        float ps = 0.f, pd = 0.f;
        if (lane < 16) {
            ps = v0 * vv[4 * li] + v1 * vv[4 * li + 1] + v2 * vv[4 * li + 2] + v3 * vv[4 * li + 3];
            pd = v0 * vv[64 + 4 * li] + v1 * vv[64 + 4 * li + 1] +
                 v2 * vv[64 + 4 * li + 2] + v3 * vv[64 + 4 * li + 3];
        }
        ps = waveReduce(ps);
        pd = waveReduce(pd);
        if (lane == 0) { fs2[wv] = ps; fd2[wv] = pd; }
    }
}

// ---------------- output (bf16 X inputs) ----------------
__global__ void final_kernel(const short* __restrict__ twX, const short* __restrict__ tuX,
                             const int* __restrict__ twi, const int* __restrict__ tui,
                             const float* __restrict__ attsum,
                             const float* __restrict__ outW, const float* __restrict__ outb,
                             float* __restrict__ out, int B, float invNtw, float invNuv) {
    int wave = (blockIdx.x * blockDim.x + threadIdx.x) >> 6;
    int lane = threadIdx.x & 63;
    if (wave >= B) return;
    float z0 = attsum[0] * invNtw, z1 = attsum[1] * invNuv;
    float m = fmaxf(z0, z1);
    float e0 = expf(z0 - m), e1 = expf(z1 - m);
    float a0 = e0 / (e0 + e1), a1 = e1 / (e0 + e1);
    int ti = twi[wave], ui = tui[wave];
    float l0 = 0.f, l1 = 0.f;
#pragma unroll
    for (int p = 0; p < 2; ++p) {
        int j = lane + 64 * p;
        float feat = a0 * bf2f(twX[(size_t)ti * 128 + j]) + a1 * bf2f(tuX[(size_t)ui * 128 + j]);
        l0 += feat * outW[j];
        l1 += feat * outW[128 + j];
    }
    l0 = waveReduce(l0);
    l1 = waveReduce(l1);
    if (lane == 0) {
        l0 += outb[0];
        l1 += outb[1];
        float mm = fmaxf(l0, l1);
        float lse = mm + logf(expf(l0 - mm) + expf(l1 - mm));
        out[wave * 2 + 0] = l0 - lse;
        out[wave * 2 + 1] = l1 - lse;
    }
}

extern "C" void kernel_launch(void* const* d_in, const int* in_sizes, int n_in,
                              void* d_out, int out_size, void* d_ws, size_t ws_size,
                              hipStream_t stream) {
    const int* features_index = (const int*)d_in[0];
    const int* tw_edges = (const int*)d_in[1];
    const int* ut_edges = (const int*)d_in[2];
    const int* tw_gidx = (const int*)d_in[3];
    const int* ut_gidx = (const int*)d_in[4];
    const float* word_emb = (const float*)d_in[5];
    const float* user_emb = (const float*)d_in[6];
    const float* tw_W1 = (const float*)d_in[7];
    const float* tw_a1 = (const float*)d_in[8];
    const float* tw_W2 = (const float*)d_in[9];
    const float* tw_a2 = (const float*)d_in[10];
    const float* tu_W1 = (const float*)d_in[11];
    const float* tu_a1 = (const float*)d_in[12];
    const float* tu_W2 = (const float*)d_in[13];
    const float* tu_a2 = (const float*)d_in[14];
    const float* weight_W = (const float*)d_in[15];
    const float* weight_proj = (const float*)d_in[16];
    const float* out_W = (const float*)d_in[17];
    const float* out_b = (const float*)d_in[18];

    const int E = in_sizes[1] / 2;              // 800000
    const int NTW = in_sizes[0] / 16;           // 50000
    const int VOCAB = in_sizes[5] / 300;        // 50000
    const int UV = in_sizes[6] / 300;           // 50000
    const int B = in_sizes[3];                  // 4096
    const int N2 = NTW + UV;
    const bool packOK = (NTW < 65536) && (UV < 65536);

    char* ws = (char*)d_ws;
    size_t off = 0;
    auto carve = [&](size_t bytes) -> void* {
        void* p = ws + off;
        off += (bytes + 255) & ~(size_t)255;
        return p;
    };
    float* Pbuf = (float*)carve((size_t)VOCAB * 64 * sizeof(float));     // 12.8 MB region (bf16 P)
    short* Hb1 = (short*)carve((size_t)N2 * 64 * sizeof(short));         // layer-1 h, both graphs
    short* Y = (short*)carve((size_t)N2 * 64 * sizeof(short));           // layer-2 aggregated x1 (pre-GEMM)
    short* X = (short*)carve((size_t)N2 * 128 * sizeof(short));          // final features
    float* f_s = (float*)carve((size_t)N2 * sizeof(float));
    float* f_d = (float*)carve((size_t)N2 * sizeof(float));
    float* f_s2 = (float*)carve((size_t)N2 * sizeof(float));
    float* f_d2 = (float*)carve((size_t)N2 * sizeof(float));
    float* attsum = (float*)carve(256);
    float* vab = (float*)carve(256 * sizeof(float));
    int* cursor = (int*)carve((size_t)N2 * sizeof(int));
    int* ecol = (int*)carve((size_t)N2 * CAP * sizeof(int));             // 25.6 MB buckets
    uint32* epkA = (uint32*)carve((size_t)E * sizeof(uint32));           // packed tweet edges
    uint32* epkB = (uint32*)carve((size_t)E * sizeof(uint32));           // packed user edges
    short* Wt1tw = (short*)carve((size_t)64 * 320 * sizeof(short));
    short* Wt1tu = (short*)carve((size_t)64 * 320 * sizeof(short));
    short* Wt2tw = (short*)carve((size_t)128 * 64 * sizeof(short));
    short* Wt2tu = (short*)carve((size_t)128 * 64 * sizeof(short));
    short* Wta   = (short*)carve((size_t)128 * 128 * sizeof(short));
    // num1 (N2*64 bf16 = 12.8 MB) aliases the Pbuf region: P's last read (gather_h64)
    // precedes the agg64 write on the same stream.
    short* num1 = ((size_t)VOCAB * 64 * sizeof(float) >= (size_t)N2 * 64 * sizeof(short))
                      ? (short*)Pbuf
                      : (short*)carve((size_t)N2 * 64 * sizeof(short));
    (void)ws_size; (void)n_in; (void)out_size;

    // ---- weight transposes + cursor init + attsum clear + vab + edge prepack (one launch) ----
    WJobs jb;
    jb.src[0] = tw_W1;    jb.dst[0] = Wt1tw; jb.K[0] = 300; jb.N[0] = 64;  jb.KP[0] = 320; jb.total[0] = 64 * 320;
    jb.src[1] = tu_W1;    jb.dst[1] = Wt1tu; jb.K[1] = 300; jb.N[1] = 64;  jb.KP[1] = 320; jb.total[1] = 64 * 320;
    jb.src[2] = tw_W2;    jb.dst[2] = Wt2tw; jb.K[2] = 64;  jb.N[2] = 128; jb.KP[2] = 64;  jb.total[2] = 128 * 64;
    jb.src[3] = tu_W2;    jb.dst[3] = Wt2tu; jb.K[3] = 64;  jb.N[3] = 128; jb.KP[3] = 64;  jb.total[3] = 128 * 64;
    jb.src[4] = weight_W; jb.dst[4] = Wta;   jb.K[4] = 128; jb.N[4] = 128; jb.KP[4] = 128; jb.total[4] = 128 * 128;
    jb.cursor = cursor;
    jb.attsum = attsum;
    jb.vab = vab;
    jb.W2tw = tw_W2; jb.a2tw = tw_a2;
    jb.W2tu = tu_W2; jb.a2tu = tu_a2;
    jb.N2 = N2;
    jb.rowA = tw_edges; jb.colA = tw_edges + E;
    jb.rowB = ut_edges; jb.colB = ut_edges + E;
    jb.epkA = packOK ? epkA : nullptr;
    jb.epkB = packOK ? epkB : nullptr;
    jb.E = E;
    {
        int gx = (64 * 320 + 255) / 256;
        int gc = (N2 + 255) / 256;
        int ge = packOK ? (E + 255) / 256 : 0;
        if (gc > gx) gx = gc;
        if (ge > gx) gx = ge;
        dim3 g(gx, 8);
        wtrans_all<<<g, 256, 0, stream>>>(jb);
    }

    SJob sempty{nullptr, nullptr, nullptr, nullptr, 0, 0, 0, 0, 0, 0};

    // ---- layer-1 projections + packed XCD-windowed scatter as grid tail ----
    if (packOK) {
        GJob a{word_emb, Wt1tw, nullptr, Pbuf, nullptr, nullptr, VOCAB};
        GJob b{user_emb, Wt1tu, tu_a1, Hb1 + (size_t)NTW * 64, f_s + NTW, f_d + NTW, UV};
        int nbw = (VOCAB + 63) / 64, nbu = (UV + 63) / 64;
        int nbg = nbw + nbu;
        int nsc = 8 * ((E + 255) / 256);
        SJob sj{epkA, epkB, cursor, ecol, E, NTW, UV, (NTW + 3) / 4, (UV + 3) / 4, nbg};
        mfma_gemm<float, 300, 320, 64, 2, true, false, true><<<nbg + nsc, 256, 0, stream>>>(
            a, b, nbw, nullptr, nullptr, sj);
    } else {
        // fallback: standalone raw scatter then plain GEMM
        int nchunk = (2 * E + 255) / 256;
        int Wsize = (N2 + 7) / 8;
        scatter8_kernel<<<8 * nchunk, 256, 0, stream>>>(tw_edges, tw_edges + E,
                                                        ut_edges, ut_edges + E,
                                                        cursor, ecol, E, NTW, Wsize);
        GJob a{word_emb, Wt1tw, nullptr, Pbuf, nullptr, nullptr, VOCAB};
        GJob b{user_emb, Wt1tu, tu_a1, Hb1 + (size_t)NTW * 64, f_s + NTW, f_d + NTW, UV};
        int nbw = (VOCAB + 63) / 64, nbu = (UV + 63) / 64;
        mfma_gemm<float, 300, 320, 64, 2, true, false, false><<<nbw + nbu, 256, 0, stream>>>(
            a, b, nbw, nullptr, nullptr, sempty);
    }
    gather_h64<<<(NTW + 3) / 4, 256, 0, stream>>>(features_index, (const uint32*)Pbuf, tw_a1,
                                                  Hb1, f_s, f_d, NTW);

    // ---- layer-1 aggregation (elu) + fused layer-2 fs/fd epilogue ----
    agg64t_kernel<true, true><<<(N2 + 3) / 4, 256, 0, stream>>>(
        cursor, ecol, f_s, f_d, (const uint32*)Hb1, (uint32*)num1, vab, f_s2, f_d2, N2, NTW);

    // ---- layer-2 aggregation over 64-dim x1 (aggregation/projection commute) ----
    agg64t_kernel<false, false><<<(N2 + 3) / 4, 256, 0, stream>>>(
        cursor, ecol, f_s2, f_d2, (const uint32*)num1, (uint32*)Y, nullptr, nullptr, nullptr,
        N2, NTW);

    // ---- layer-2 GEMM: X = elu(Y @ W2) with FUSED attention reduce (X@Wta, tanh, proj) ----
    {
        int nbtw = (NTW + 63) / 64, nbtu = (UV + 63) / 64;
        GJob a{Y, Wt2tw, weight_proj, X, nullptr, nullptr, NTW};
        GJob b{Y + (size_t)NTW * 64, Wt2tu, weight_proj, X + (size_t)NTW * 128,
               nullptr, nullptr, UV};
        mfma_gemm<short, 64, 64, 128, 3, false, true, false><<<nbtw + nbtu, 256, 0, stream>>>(
            a, b, nbtw, attsum, Wta, sempty);
    }

    final_kernel<<<(B + 3) / 4, 256, 0, stream>>>(X, X + (size_t)NTW * 128, tw_gidx, ut_gidx,
                                                  attsum, out_W, out_b, (float*)d_out, B,
                                                  1.0f / (float)NTW, 1.0f / (float)UV);
}